// Round 6
// baseline (158.031 us; speedup 1.0000x reference)
//
#include <hip/hip_runtime.h>

// GAT layer, N=8192, F_in=512, F_out=256.
// Pipeline: k_u -> k_rowvec (wh1,wh2 pre-scaled by log2e, blockmax)
//   -> k_wh (whT bf16 GEMM; block 0 also reduces pmax->gmax)
//   -> k_attn (streams adj; P-in-registers, 32-row waves share fb reads;
//      2-slot global_load_lds ring + vmcnt(8) fence; 2 blocks/CU; split-K=4)
//   -> k_out (combine 4 partials + elu)

typedef __attribute__((ext_vector_type(8))) short short8;
typedef __attribute__((ext_vector_type(4))) float f32x4;

#define LOG2E 1.4426950408889634f

__device__ __forceinline__ unsigned short f2bf(float f) {
  unsigned int u = __float_as_uint(f);
  unsigned int r = u + 0x7FFFu + ((u >> 16) & 1u);  // RNE
  return (unsigned short)(r >> 16);
}

// ---------------- u1 = W^T a1, u2 = W^T a2 (512 each), atomic-free ----------------
__global__ __launch_bounds__(512) void k_u(const float* __restrict__ W,
                                           const float* __restrict__ a1,
                                           const float* __restrict__ a2,
                                           float* __restrict__ u1,
                                           float* __restrict__ u2) {
  __shared__ float p1[16][32], p2[16][32];
  const int tid = threadIdx.x;
  const int kk = tid & 31, og = tid >> 5;
  const int k0 = blockIdx.x * 32;  // grid 16
  float s1 = 0.f, s2 = 0.f;
#pragma unroll
  for (int j = 0; j < 16; j++) {
    const int o = og * 16 + j;
    const float w = W[(size_t)o * 512 + k0 + kk];
    s1 += w * a1[o];
    s2 += w * a2[o];
  }
  p1[og][kk] = s1;
  p2[og][kk] = s2;
  __syncthreads();
  if (tid < 32) {
    float t1 = 0.f, t2 = 0.f;
#pragma unroll
    for (int g = 0; g < 16; g++) { t1 += p1[g][tid]; t2 += p2[g][tid]; }
    u1[k0 + tid] = t1;
    u2[k0 + tid] = t2;
  }
}

// --- wh1[i]=h_i.u1 * log2e, wh2[i]=h_i.u2 * log2e, per-block max(wh2) ---
__global__ __launch_bounds__(256) void k_rowvec(const float* __restrict__ h,
                                                const float* __restrict__ u1,
                                                const float* __restrict__ u2,
                                                float* __restrict__ wh1,
                                                float* __restrict__ wh2,
                                                float* __restrict__ pmax) {
  __shared__ float su1[512], su2[512];
  __shared__ float smax[4];
  const int tid = threadIdx.x;
  for (int i = tid; i < 512; i += 256) { su1[i] = u1[i]; su2[i] = u2[i]; }
  __syncthreads();
  const int lane = tid & 63;
  const int row = blockIdx.x * 4 + (tid >> 6);  // grid 2048
  const float* hp = h + (size_t)row * 512 + lane * 8;
  float4 x0 = *(const float4*)hp;
  float4 x1 = *(const float4*)(hp + 4);
  const float* q1 = su1 + lane * 8;
  const float* q2 = su2 + lane * 8;
  float s1 = x0.x * q1[0] + x0.y * q1[1] + x0.z * q1[2] + x0.w * q1[3]
           + x1.x * q1[4] + x1.y * q1[5] + x1.z * q1[6] + x1.w * q1[7];
  float s2 = x0.x * q2[0] + x0.y * q2[1] + x0.z * q2[2] + x0.w * q2[3]
           + x1.x * q2[4] + x1.y * q2[5] + x1.z * q2[6] + x1.w * q2[7];
#pragma unroll
  for (int off = 32; off >= 1; off >>= 1) {
    s1 += __shfl_xor(s1, off);
    s2 += __shfl_xor(s2, off);
  }
  if (lane == 0) {
    wh1[row] = s1 * LOG2E;
    wh2[row] = s2 * LOG2E;
    smax[tid >> 6] = s2 * LOG2E;
  }
  __syncthreads();
  if (tid == 0)
    pmax[blockIdx.x] = fmaxf(fmaxf(smax[0], smax[1]), fmaxf(smax[2], smax[3]));
}

// ------- whT[n][m] = (h @ W^T)[m][n] in bf16; block 0 also reduces pmax -> gmax -------
__global__ __launch_bounds__(512, 1) void k_wh(const float* __restrict__ h,
                                               const float* __restrict__ W,
                                               unsigned short* __restrict__ whT,
                                               const float* __restrict__ pmax,
                                               float* __restrict__ gmax) {
  __shared__ uint4 lds[2560];
  __shared__ float sred[8];
  const int tid = threadIdx.x;
  if (blockIdx.x == 0) {  // fold k_max: reduce pmax[2048] -> gmax
    float m = -3.0e38f;
    for (int i = tid; i < 2048; i += 512) m = fmaxf(m, pmax[i]);
#pragma unroll
    for (int off = 32; off >= 1; off >>= 1) m = fmaxf(m, __shfl_xor(m, off));
    if ((tid & 63) == 0) sred[tid >> 6] = m;
    __syncthreads();
    if (tid == 0) {
      float g = sred[0];
#pragma unroll
      for (int i = 1; i < 8; i++) g = fmaxf(g, sred[i]);
      gmax[0] = g;
    }
  }
  const int i0 = blockIdx.x * 64;  // grid 128
  const int lane = tid & 63, wid = tid >> 6;
  const int wm = wid >> 2, wn = wid & 3;
  const int l16 = lane & 15, lq = lane >> 4;
  const int hr = tid >> 3, hc = tid & 7;
  const int wr = tid >> 1, wc = tid & 1;

  f32x4 acc[2][4] = {};

  for (int t = 0; t < 8; t++) {
    const int k0 = t * 64;
    const float* hp = h + (size_t)(i0 + hr) * 512 + k0 + hc * 8;
    float4 hx = *(const float4*)hp;
    float4 hy = *(const float4*)(hp + 4);
    const float* wp = W + (size_t)wr * 512 + k0 + wc * 32;
    float4 wv[8];
#pragma unroll
    for (int q = 0; q < 8; q++) wv[q] = *(const float4*)(wp + q * 4);

    __syncthreads();
    uint4 hw;
    hw.x = (unsigned)f2bf(hx.x) | ((unsigned)f2bf(hx.y) << 16);
    hw.y = (unsigned)f2bf(hx.z) | ((unsigned)f2bf(hx.w) << 16);
    hw.z = (unsigned)f2bf(hy.x) | ((unsigned)f2bf(hy.y) << 16);
    hw.w = (unsigned)f2bf(hy.z) | ((unsigned)f2bf(hy.w) << 16);
    lds[hr * 8 + (hc ^ (hr & 7))] = hw;
#pragma unroll
    for (int q = 0; q < 4; q++) {
      uint4 ww;
      ww.x = (unsigned)f2bf(wv[2 * q].x) | ((unsigned)f2bf(wv[2 * q].y) << 16);
      ww.y = (unsigned)f2bf(wv[2 * q].z) | ((unsigned)f2bf(wv[2 * q].w) << 16);
      ww.z = (unsigned)f2bf(wv[2 * q + 1].x) | ((unsigned)f2bf(wv[2 * q + 1].y) << 16);
      ww.w = (unsigned)f2bf(wv[2 * q + 1].z) | ((unsigned)f2bf(wv[2 * q + 1].w) << 16);
      lds[512 + wr * 8 + ((wc * 4 + q) ^ (wr & 7))] = ww;
    }
    __syncthreads();
#pragma unroll
    for (int ks = 0; ks < 2; ks++) {
      const int r0 = wm * 32 + l16, r1 = r0 + 16;
      short8 fa0 = *(const short8*)&lds[r0 * 8 + ((ks * 4 + lq) ^ (r0 & 7))];
      short8 fa1 = *(const short8*)&lds[r1 * 8 + ((ks * 4 + lq) ^ (r1 & 7))];
#pragma unroll
      for (int fn = 0; fn < 4; fn++) {
        const int bn = wn * 64 + fn * 16 + l16;
        short8 fb = *(const short8*)&lds[512 + bn * 8 + ((ks * 4 + lq) ^ (bn & 7))];
        acc[0][fn] = __builtin_amdgcn_mfma_f32_16x16x32_bf16(fa0, fb, acc[0][fn], 0, 0, 0);
        acc[1][fn] = __builtin_amdgcn_mfma_f32_16x16x32_bf16(fa1, fb, acc[1][fn], 0, 0, 0);
      }
    }
  }
#pragma unroll
  for (int fm = 0; fm < 2; fm++) {
#pragma unroll
    for (int fn = 0; fn < 4; fn++) {
      const int n = wn * 64 + fn * 16 + l16;
      const int m0 = i0 + wm * 32 + fm * 16 + lq * 4;
      uint2 o;
      o.x = (unsigned)f2bf(acc[fm][fn][0]) | ((unsigned)f2bf(acc[fm][fn][1]) << 16);
      o.y = (unsigned)f2bf(acc[fm][fn][2]) | ((unsigned)f2bf(acc[fm][fn][3]) << 16);
      *(uint2*)(whT + (size_t)n * 8192 + m0) = o;
    }
  }
}

// ---------------- fused masked softmax-numerator x wh ----------------
// grid 512 = 128 row-blocks (BM=64) x 4 K-splits (2048 j); 128 thr (2 waves x 32 rows).
struct PFR {
  int4 l0, l1, l2, l3, h0, h1, h2, h3;  // adj for lo/hi rows, 16 j each
};

__global__ __launch_bounds__(128, 1) void k_attn(
    const int* __restrict__ adj, const unsigned short* __restrict__ whT,
    const float* __restrict__ wh1v, const float* __restrict__ wh2v,
    const float* __restrict__ gmax,
    float* __restrict__ out0, float* __restrict__ out1,
    float* __restrict__ out2, float* __restrict__ out3,
    float* __restrict__ denp) {
  __shared__ uint4 ring[2][2048];  // 2 x 32KB whT tile [256 n][64 j] bf16
  __shared__ float wh2s[2048];     // this split's wh2 slice (log2e-scaled)
  const int NT = 32;
  const int tid = threadIdx.x;
  const int bid = blockIdx.x;
  // XCD-clustered: same sb on same XCD pair -> whT slice L2-resident
  const int sb = (bid & 7) >> 1;
  const int mb = ((bid >> 3) << 1) | (bid & 1);  // 0..127
  const int i0 = mb * 64;
  const int jbase = sb * 2048;
  const int lane = tid & 63, w = tid >> 6;
  const int l16 = lane & 15, q = lane >> 4;
  const int row_lo = i0 + w * 32 + l16;

  for (int i = tid; i < 512; i += 128)
    ((float4*)wh2s)[i] = ((const float4*)(wh2v + jbase))[i];

  const float M2 = gmax[0];
  const float w1lo = wh1v[row_lo];
  const float w1hi = wh1v[row_lo + 16];
  float tv = w1lo + M2;
  const float Milo = tv > 0.f ? tv : 0.2f * tv;
  tv = w1hi + M2;
  const float Mihi = tv > 0.f ? tv : 0.2f * tv;
  const float c1lo = w1lo - Milo, c2lo = 0.2f * w1lo - Milo;
  const float c1hi = w1hi - Mihi, c2hi = 0.2f * w1hi - Mihi;

  const int* ap_lo = adj + (size_t)row_lo * 8192 + jbase + q * 8;
  const int* ap_hi = ap_lo + 16 * 8192;

  f32x4 accL[16] = {}, accH[16] = {};
  float dsL = 0.f, dsH = 0.f;
  short8 paL0, paL1, paH0, paH1;
  PFR PA, PB;

#define PFLOAD(R, T)                              \
  do {                                            \
    const int o_ = (((T) < NT) ? (T) : 0) * 64;   \
    R.l0 = *(const int4*)(ap_lo + o_);            \
    R.l1 = *(const int4*)(ap_lo + o_ + 4);        \
    R.l2 = *(const int4*)(ap_lo + o_ + 32);       \
    R.l3 = *(const int4*)(ap_lo + o_ + 36);       \
    R.h0 = *(const int4*)(ap_hi + o_);            \
    R.h1 = *(const int4*)(ap_hi + o_ + 4);        \
    R.h2 = *(const int4*)(ap_hi + o_ + 32);       \
    R.h3 = *(const int4*)(ap_hi + o_ + 36);       \
  } while (0)

#define COMPUTE(R, T)                                                          \
  do {                                                                         \
    const int o_ = (((T) < NT) ? (T) : 0) * 64 + q * 8;                        \
    float4 z0 = *(const float4*)(wh2s + o_);                                   \
    float4 z1 = *(const float4*)(wh2s + o_ + 4);                               \
    float4 z2 = *(const float4*)(wh2s + o_ + 32);                              \
    float4 z3 = *(const float4*)(wh2s + o_ + 36);                              \
    float zv[16] = {z0.x, z0.y, z0.z, z0.w, z1.x, z1.y, z1.z, z1.w,            \
                    z2.x, z2.y, z2.z, z2.w, z3.x, z3.y, z3.z, z3.w};           \
    int al[16] = {R.l0.x, R.l0.y, R.l0.z, R.l0.w, R.l1.x, R.l1.y, R.l1.z,      \
                  R.l1.w, R.l2.x, R.l2.y, R.l2.z, R.l2.w, R.l3.x, R.l3.y,      \
                  R.l3.z, R.l3.w};                                             \
    int ah[16] = {R.h0.x, R.h0.y, R.h0.z, R.h0.w, R.h1.x, R.h1.y, R.h1.z,      \
                  R.h1.w, R.h2.x, R.h2.y, R.h2.z, R.h2.w, R.h3.x, R.h3.y,      \
                  R.h3.z, R.h3.w};                                             \
    float pl[16], ph[16];                                                      \
    _Pragma("unroll") for (int i = 0; i < 16; i++) {                           \
      float e1 = fmaxf(c1lo + zv[i], __builtin_fmaf(0.2f, zv[i], c2lo));       \
      float p = (al[i] > 0) ? __builtin_amdgcn_exp2f(e1) : 0.f;                \
      pl[i] = p;                                                               \
      dsL += p;                                                                \
      float e2 = fmaxf(c1hi + zv[i], __builtin_fmaf(0.2f, zv[i], c2hi));       \
      p = (ah[i] > 0) ? __builtin_amdgcn_exp2f(e2) : 0.f;                      \
      ph[i] = p;                                                               \
      dsH += p;                                                                \
    }                                                                          \
    _Pragma("unroll") for (int i = 0; i < 8; i++) {                            \
      paL0[i] = (short)f2bf(pl[i]);                                            \
      paL1[i] = (short)f2bf(pl[8 + i]);                                        \
      paH0[i] = (short)f2bf(ph[i]);                                            \
      paH1[i] = (short)f2bf(ph[8 + i]);                                        \
    }                                                                          \
  } while (0)

#define STAGE(TT, SLOT)                                                        \
  do {                                                                         \
    const int tt_ = ((TT) < NT) ? (TT) : 0;                                    \
    const size_t gj_ = (size_t)(jbase + tt_ * 64);                             \
    _Pragma("unroll") for (int kq = 0; kq < 16; kq++) {                        \
      const int L = kq * 128 + tid;                                            \
      const int row = L >> 3, sub = L & 7;                                     \
      const int boff = (sub * 16) ^ ((row & 7) << 4);                          \
      const char* src_ = (const char*)(whT + (size_t)row * 8192 + gj_) + boff; \
      char* dst_ = (char*)ring[SLOT] + L * 16;                                 \
      __builtin_amdgcn_global_load_lds(                                        \
          (const __attribute__((address_space(1))) unsigned int*)src_,         \
          (__attribute__((address_space(3))) unsigned int*)dst_, 16, 0, 0);    \
    }                                                                          \
  } while (0)

#define FENCE asm volatile("s_waitcnt vmcnt(8)" ::: "memory")

#define MFMAPH(SLOT)                                                           \
  do {                                                                         \
    const char* lb_ = (const char*)ring[SLOT];                                 \
    _Pragma("unroll") for (int nb = 0; nb < 16; nb++) {                        \
      const int n_ = nb * 16 + l16;                                            \
      const int rb_ = n_ * 128;                                                \
      const int sw_ = (n_ & 7) << 4;                                           \
      short8 fb0 = *(const short8*)(lb_ + rb_ + ((q * 16) ^ sw_));             \
      short8 fb1 = *(const short8*)(lb_ + rb_ + ((64 + q * 16) ^ sw_));        \
      accL[nb] = __builtin_amdgcn_mfma_f32_16x16x32_bf16(paL0, fb0, accL[nb], 0, 0, 0); \
      accL[nb] = __builtin_amdgcn_mfma_f32_16x16x32_bf16(paL1, fb1, accL[nb], 0, 0, 0); \
      accH[nb] = __builtin_amdgcn_mfma_f32_16x16x32_bf16(paH0, fb0, accH[nb], 0, 0, 0); \
      accH[nb] = __builtin_amdgcn_mfma_f32_16x16x32_bf16(paH1, fb1, accH[nb], 0, 0, 0); \
    }                                                                          \
  } while (0)

  // prologue
  PFLOAD(PA, 0);
  STAGE(0, 0);
  __syncthreads();  // wh2s visible

  for (int t = 0; t < NT; t += 2) {
    // even round: reads ring[0]
    PFLOAD(PB, t + 1);
    COMPUTE(PA, t);
    FENCE;
    __builtin_amdgcn_s_barrier();
    STAGE(t + 1, 1);
    MFMAPH(0);
    // odd round: reads ring[1]
    PFLOAD(PA, t + 2);
    COMPUTE(PB, t + 1);
    FENCE;
    __builtin_amdgcn_s_barrier();
    STAGE(t + 2, 0);
    MFMAPH(1);
  }

#undef PFLOAD
#undef COMPUTE
#undef STAGE
#undef FENCE
#undef MFMAPH

  float* outp = (sb == 0) ? out0 : (sb == 1) ? out1 : (sb == 2) ? out2 : out3;
  const int r0 = i0 + w * 32 + q * 4;
#pragma unroll
  for (int nb = 0; nb < 16; nb++) {
    const int col = nb * 16 + l16;
#pragma unroll
    for (int r = 0; r < 4; r++) {
      outp[(size_t)(r0 + r) * 256 + col] = accL[nb][r];
      outp[(size_t)(r0 + 16 + r) * 256 + col] = accH[nb][r];
    }
  }

  dsL += __shfl_xor(dsL, 16);
  dsL += __shfl_xor(dsL, 32);
  dsH += __shfl_xor(dsH, 16);
  dsH += __shfl_xor(dsH, 32);
  if (lane < 16) {
    denp[sb * 8192 + i0 + w * 32 + lane] = dsL;
    denp[sb * 8192 + i0 + w * 32 + 16 + lane] = dsH;
  }
}

// ---------------- combine split-K partials, divide by denom, elu ----------------
__global__ __launch_bounds__(256) void k_out(float* __restrict__ out,
                                             const float* __restrict__ p1,
                                             const float* __restrict__ p2,
                                             const float* __restrict__ p3,
                                             const float* __restrict__ denp) {
  const int idx = blockIdx.x * 256 + threadIdx.x;  // grid 2048
  const int row = idx >> 6;
  float4 o = ((const float4*)out)[idx];
  float4 a = ((const float4*)p1)[idx];
  float4 b = ((const float4*)p2)[idx];
  float4 c = ((const float4*)p3)[idx];
  const float inv =
      1.0f / (denp[row] + denp[8192 + row] + denp[16384 + row] + denp[24576 + row]);
  float v0 = (o.x + a.x + b.x + c.x) * inv;
  float v1 = (o.y + a.y + b.y + c.y) * inv;
  float v2 = (o.z + a.z + b.z + c.z) * inv;
  float v3 = (o.w + a.w + b.w + c.w) * inv;
  v0 = v0 > 0.f ? v0 : expm1f(v0);
  v1 = v1 > 0.f ? v1 : expm1f(v1);
  v2 = v2 > 0.f ? v2 : expm1f(v2);
  v3 = v3 > 0.f ? v3 : expm1f(v3);
  ((float4*)out)[idx] = make_float4(v0, v1, v2, v3);
}

extern "C" void kernel_launch(void* const* d_in, const int* in_sizes, int n_in,
                              void* d_out, int out_size, void* d_ws, size_t ws_size,
                              hipStream_t stream) {
  const float* h = (const float*)d_in[0];
  const float* W = (const float*)d_in[1];
  const float* a1 = (const float*)d_in[2];
  const float* a2 = (const float*)d_in[3];
  const int* adj = (const int*)d_in[4];
  float* out = (float*)d_out;
  char* ws = (char*)d_ws;

  // ws: [whT 4MB][p1 8MB][p2 8MB][p3 8MB][denp 128K][wh1][wh2][pmax][u1][u2][gmax]
  unsigned short* whT = (unsigned short*)ws;
  float* part1 = (float*)(ws + (4u << 20));
  float* part2 = (float*)(ws + (12u << 20));
  float* part3 = (float*)(ws + (20u << 20));
  float* denp = (float*)(ws + (28u << 20));  // 4*8192
  float* wh1 = denp + 4 * 8192;
  float* wh2 = wh1 + 8192;
  float* pmax = wh2 + 8192;  // 2048
  float* u1 = pmax + 2048;
  float* u2 = u1 + 512;
  float* gmax = u2 + 512;

  hipLaunchKernelGGL(k_u, dim3(16), dim3(512), 0, stream, W, a1, a2, u1, u2);
  hipLaunchKernelGGL(k_rowvec, dim3(2048), dim3(256), 0, stream, h, u1, u2, wh1,
                     wh2, pmax);
  hipLaunchKernelGGL(k_wh, dim3(128), dim3(512), 0, stream, h, W, whT, pmax, gmax);
  hipLaunchKernelGGL(k_attn, dim3(512), dim3(128), 0, stream, adj, whT, wh1,
                     wh2, gmax, out, part1, part2, part3, denp);
  hipLaunchKernelGGL(k_out, dim3(2048), dim3(256), 0, stream, out, part1, part2,
                     part3, denp);
  (void)in_sizes; (void)n_in; (void)out_size; (void)ws_size;
}

// Round 7
// 153.439 us; speedup vs baseline: 1.0299x; 1.0299x over previous
//
#include <hip/hip_runtime.h>

// GAT layer, N=8192, F_in=512, F_out=256.
// Pipeline: k_u -> k_rowvec (wh1,wh2 pre-scaled by log2e, blockmax)
//   -> k_wh (whT bf16 GEMM; block 0 also reduces pmax->gmax)
//   -> k_attn (streams adj; P-in-registers; 8 waves = 4 row-groups x 2 col-halves,
//      fb reads shared by lo/hi row-frags; 2-slot global_load_lds ring + vmcnt(8) fence)
//   -> k_out (combine 4 partials + elu)

typedef __attribute__((ext_vector_type(8))) short short8;
typedef __attribute__((ext_vector_type(4))) float f32x4;

#define LOG2E 1.4426950408889634f

__device__ __forceinline__ unsigned short f2bf(float f) {
  unsigned int u = __float_as_uint(f);
  unsigned int r = u + 0x7FFFu + ((u >> 16) & 1u);  // RNE
  return (unsigned short)(r >> 16);
}

// ---------------- u1 = W^T a1, u2 = W^T a2 (512 each), atomic-free ----------------
__global__ __launch_bounds__(512) void k_u(const float* __restrict__ W,
                                           const float* __restrict__ a1,
                                           const float* __restrict__ a2,
                                           float* __restrict__ u1,
                                           float* __restrict__ u2) {
  __shared__ float p1[16][32], p2[16][32];
  const int tid = threadIdx.x;
  const int kk = tid & 31, og = tid >> 5;
  const int k0 = blockIdx.x * 32;  // grid 16
  float s1 = 0.f, s2 = 0.f;
#pragma unroll
  for (int j = 0; j < 16; j++) {
    const int o = og * 16 + j;
    const float w = W[(size_t)o * 512 + k0 + kk];
    s1 += w * a1[o];
    s2 += w * a2[o];
  }
  p1[og][kk] = s1;
  p2[og][kk] = s2;
  __syncthreads();
  if (tid < 32) {
    float t1 = 0.f, t2 = 0.f;
#pragma unroll
    for (int g = 0; g < 16; g++) { t1 += p1[g][tid]; t2 += p2[g][tid]; }
    u1[k0 + tid] = t1;
    u2[k0 + tid] = t2;
  }
}

// --- wh1[i]=h_i.u1 * log2e, wh2[i]=h_i.u2 * log2e, per-block max(wh2) ---
__global__ __launch_bounds__(256) void k_rowvec(const float* __restrict__ h,
                                                const float* __restrict__ u1,
                                                const float* __restrict__ u2,
                                                float* __restrict__ wh1,
                                                float* __restrict__ wh2,
                                                float* __restrict__ pmax) {
  __shared__ float su1[512], su2[512];
  __shared__ float smax[4];
  const int tid = threadIdx.x;
  for (int i = tid; i < 512; i += 256) { su1[i] = u1[i]; su2[i] = u2[i]; }
  __syncthreads();
  const int lane = tid & 63;
  const int row = blockIdx.x * 4 + (tid >> 6);  // grid 2048
  const float* hp = h + (size_t)row * 512 + lane * 8;
  float4 x0 = *(const float4*)hp;
  float4 x1 = *(const float4*)(hp + 4);
  const float* q1 = su1 + lane * 8;
  const float* q2 = su2 + lane * 8;
  float s1 = x0.x * q1[0] + x0.y * q1[1] + x0.z * q1[2] + x0.w * q1[3]
           + x1.x * q1[4] + x1.y * q1[5] + x1.z * q1[6] + x1.w * q1[7];
  float s2 = x0.x * q2[0] + x0.y * q2[1] + x0.z * q2[2] + x0.w * q2[3]
           + x1.x * q2[4] + x1.y * q2[5] + x1.z * q2[6] + x1.w * q2[7];
#pragma unroll
  for (int off = 32; off >= 1; off >>= 1) {
    s1 += __shfl_xor(s1, off);
    s2 += __shfl_xor(s2, off);
  }
  if (lane == 0) {
    wh1[row] = s1 * LOG2E;
    wh2[row] = s2 * LOG2E;
    smax[tid >> 6] = s2 * LOG2E;
  }
  __syncthreads();
  if (tid == 0)
    pmax[blockIdx.x] = fmaxf(fmaxf(smax[0], smax[1]), fmaxf(smax[2], smax[3]));
}

// ------- whT[n][m] = (h @ W^T)[m][n] in bf16; block 0 also reduces pmax -> gmax -------
__global__ __launch_bounds__(512, 1) void k_wh(const float* __restrict__ h,
                                               const float* __restrict__ W,
                                               unsigned short* __restrict__ whT,
                                               const float* __restrict__ pmax,
                                               float* __restrict__ gmax) {
  __shared__ uint4 lds[2560];
  __shared__ float sred[8];
  const int tid = threadIdx.x;
  if (blockIdx.x == 0) {  // fold k_max: reduce pmax[2048] -> gmax
    float m = -3.0e38f;
    for (int i = tid; i < 2048; i += 512) m = fmaxf(m, pmax[i]);
#pragma unroll
    for (int off = 32; off >= 1; off >>= 1) m = fmaxf(m, __shfl_xor(m, off));
    if ((tid & 63) == 0) sred[tid >> 6] = m;
    __syncthreads();
    if (tid == 0) {
      float g = sred[0];
#pragma unroll
      for (int i = 1; i < 8; i++) g = fmaxf(g, sred[i]);
      gmax[0] = g;
    }
  }
  const int i0 = blockIdx.x * 64;  // grid 128
  const int lane = tid & 63, wid = tid >> 6;
  const int wm = wid >> 2, wn = wid & 3;
  const int l16 = lane & 15, lq = lane >> 4;
  const int hr = tid >> 3, hc = tid & 7;
  const int wr = tid >> 1, wc = tid & 1;

  f32x4 acc[2][4] = {};

  for (int t = 0; t < 8; t++) {
    const int k0 = t * 64;
    const float* hp = h + (size_t)(i0 + hr) * 512 + k0 + hc * 8;
    float4 hx = *(const float4*)hp;
    float4 hy = *(const float4*)(hp + 4);
    const float* wp = W + (size_t)wr * 512 + k0 + wc * 32;
    float4 wv[8];
#pragma unroll
    for (int q = 0; q < 8; q++) wv[q] = *(const float4*)(wp + q * 4);

    __syncthreads();
    uint4 hw;
    hw.x = (unsigned)f2bf(hx.x) | ((unsigned)f2bf(hx.y) << 16);
    hw.y = (unsigned)f2bf(hx.z) | ((unsigned)f2bf(hx.w) << 16);
    hw.z = (unsigned)f2bf(hy.x) | ((unsigned)f2bf(hy.y) << 16);
    hw.w = (unsigned)f2bf(hy.z) | ((unsigned)f2bf(hy.w) << 16);
    lds[hr * 8 + (hc ^ (hr & 7))] = hw;
#pragma unroll
    for (int q = 0; q < 4; q++) {
      uint4 ww;
      ww.x = (unsigned)f2bf(wv[2 * q].x) | ((unsigned)f2bf(wv[2 * q].y) << 16);
      ww.y = (unsigned)f2bf(wv[2 * q].z) | ((unsigned)f2bf(wv[2 * q].w) << 16);
      ww.z = (unsigned)f2bf(wv[2 * q + 1].x) | ((unsigned)f2bf(wv[2 * q + 1].y) << 16);
      ww.w = (unsigned)f2bf(wv[2 * q + 1].z) | ((unsigned)f2bf(wv[2 * q + 1].w) << 16);
      lds[512 + wr * 8 + ((wc * 4 + q) ^ (wr & 7))] = ww;
    }
    __syncthreads();
#pragma unroll
    for (int ks = 0; ks < 2; ks++) {
      const int r0 = wm * 32 + l16, r1 = r0 + 16;
      short8 fa0 = *(const short8*)&lds[r0 * 8 + ((ks * 4 + lq) ^ (r0 & 7))];
      short8 fa1 = *(const short8*)&lds[r1 * 8 + ((ks * 4 + lq) ^ (r1 & 7))];
#pragma unroll
      for (int fn = 0; fn < 4; fn++) {
        const int bn = wn * 64 + fn * 16 + l16;
        short8 fb = *(const short8*)&lds[512 + bn * 8 + ((ks * 4 + lq) ^ (bn & 7))];
        acc[0][fn] = __builtin_amdgcn_mfma_f32_16x16x32_bf16(fa0, fb, acc[0][fn], 0, 0, 0);
        acc[1][fn] = __builtin_amdgcn_mfma_f32_16x16x32_bf16(fa1, fb, acc[1][fn], 0, 0, 0);
      }
    }
  }
#pragma unroll
  for (int fm = 0; fm < 2; fm++) {
#pragma unroll
    for (int fn = 0; fn < 4; fn++) {
      const int n = wn * 64 + fn * 16 + l16;
      const int m0 = i0 + wm * 32 + fm * 16 + lq * 4;
      uint2 o;
      o.x = (unsigned)f2bf(acc[fm][fn][0]) | ((unsigned)f2bf(acc[fm][fn][1]) << 16);
      o.y = (unsigned)f2bf(acc[fm][fn][2]) | ((unsigned)f2bf(acc[fm][fn][3]) << 16);
      *(uint2*)(whT + (size_t)n * 8192 + m0) = o;
    }
  }
}

// ---------------- fused masked softmax-numerator x wh ----------------
// grid 256 = 64 row-blocks (BM=128) x 4 K-splits (2048 j); 512 thr = 8 waves
// = 4 row-groups (32 rows) x 2 col-halves (128 cols). NT=32 rounds of BK=64 j.
struct PFR {
  int4 l0, l1, l2, l3, h0, h1, h2, h3;  // adj for lo/hi rows, 16 j each
};

__global__ __launch_bounds__(512, 2) void k_attn(
    const int* __restrict__ adj, const unsigned short* __restrict__ whT,
    const float* __restrict__ wh1v, const float* __restrict__ wh2v,
    const float* __restrict__ gmax,
    float* __restrict__ out0, float* __restrict__ out1,
    float* __restrict__ out2, float* __restrict__ out3,
    float* __restrict__ denp) {
  __shared__ uint4 ring[2][2048];  // 2 x 32KB whT tile [256 n][64 j] bf16
  __shared__ float wh2s[2048];     // this split's wh2 slice (log2e-scaled)
  const int NT = 32;
  const int tid = threadIdx.x;
  const int bid = blockIdx.x;
  // XCD-clustered: same sb on same XCD pair -> whT slice L2-resident
  const int sb = (bid & 7) >> 1;
  const int mb = ((bid >> 3) << 1) | (bid & 1);  // 0..63
  const int i0 = mb * 128;
  const int jbase = sb * 2048;
  const int lane = tid & 63, wid = tid >> 6;
  const int wm = wid >> 1, wn = wid & 1;  // 4 row-groups x 2 col-halves
  const int l16 = lane & 15, q = lane >> 4;
  const int row_lo = i0 + wm * 32 + l16;

  if (tid < 512) ((float4*)wh2s)[tid] = ((const float4*)(wh2v + jbase))[tid];

  const float M2 = gmax[0];
  const float w1lo = wh1v[row_lo];
  const float w1hi = wh1v[row_lo + 16];
  float tv = w1lo + M2;
  const float Milo = tv > 0.f ? tv : 0.2f * tv;
  tv = w1hi + M2;
  const float Mihi = tv > 0.f ? tv : 0.2f * tv;
  const float c1lo = w1lo - Milo, c2lo = 0.2f * w1lo - Milo;
  const float c1hi = w1hi - Mihi, c2hi = 0.2f * w1hi - Mihi;

  const int* ap_lo = adj + (size_t)row_lo * 8192 + jbase + q * 8;
  const int* ap_hi = ap_lo + 16 * 8192;

  f32x4 accL[8] = {}, accH[8] = {};
  float dsL = 0.f, dsH = 0.f;
  short8 paL0, paL1, paH0, paH1;
  PFR PA, PB;

#define PFLOAD(R, T)                              \
  do {                                            \
    const int o_ = (((T) < NT) ? (T) : 0) * 64;   \
    R.l0 = *(const int4*)(ap_lo + o_);            \
    R.l1 = *(const int4*)(ap_lo + o_ + 4);        \
    R.l2 = *(const int4*)(ap_lo + o_ + 32);       \
    R.l3 = *(const int4*)(ap_lo + o_ + 36);       \
    R.h0 = *(const int4*)(ap_hi + o_);            \
    R.h1 = *(const int4*)(ap_hi + o_ + 4);        \
    R.h2 = *(const int4*)(ap_hi + o_ + 32);       \
    R.h3 = *(const int4*)(ap_hi + o_ + 36);       \
  } while (0)

#define COMPUTE(R, T)                                                          \
  do {                                                                         \
    const int o_ = (((T) < NT) ? (T) : 0) * 64 + q * 8;                        \
    float4 z0 = *(const float4*)(wh2s + o_);                                   \
    float4 z1 = *(const float4*)(wh2s + o_ + 4);                               \
    float4 z2 = *(const float4*)(wh2s + o_ + 32);                              \
    float4 z3 = *(const float4*)(wh2s + o_ + 36);                              \
    float zv[16] = {z0.x, z0.y, z0.z, z0.w, z1.x, z1.y, z1.z, z1.w,            \
                    z2.x, z2.y, z2.z, z2.w, z3.x, z3.y, z3.z, z3.w};           \
    int al[16] = {R.l0.x, R.l0.y, R.l0.z, R.l0.w, R.l1.x, R.l1.y, R.l1.z,      \
                  R.l1.w, R.l2.x, R.l2.y, R.l2.z, R.l2.w, R.l3.x, R.l3.y,      \
                  R.l3.z, R.l3.w};                                             \
    int ah[16] = {R.h0.x, R.h0.y, R.h0.z, R.h0.w, R.h1.x, R.h1.y, R.h1.z,      \
                  R.h1.w, R.h2.x, R.h2.y, R.h2.z, R.h2.w, R.h3.x, R.h3.y,      \
                  R.h3.z, R.h3.w};                                             \
    float pl[16], ph[16];                                                      \
    _Pragma("unroll") for (int i = 0; i < 16; i++) {                           \
      float e1 = fmaxf(c1lo + zv[i], __builtin_fmaf(0.2f, zv[i], c2lo));       \
      float p = (al[i] > 0) ? __builtin_amdgcn_exp2f(e1) : 0.f;                \
      pl[i] = p;                                                               \
      dsL += p;                                                                \
      float e2 = fmaxf(c1hi + zv[i], __builtin_fmaf(0.2f, zv[i], c2hi));       \
      p = (ah[i] > 0) ? __builtin_amdgcn_exp2f(e2) : 0.f;                      \
      ph[i] = p;                                                               \
      dsH += p;                                                                \
    }                                                                          \
    _Pragma("unroll") for (int i = 0; i < 8; i++) {                            \
      paL0[i] = (short)f2bf(pl[i]);                                            \
      paL1[i] = (short)f2bf(pl[8 + i]);                                        \
      paH0[i] = (short)f2bf(ph[i]);                                            \
      paH1[i] = (short)f2bf(ph[8 + i]);                                        \
    }                                                                          \
  } while (0)

#define STAGE(TT, SLOT)                                                        \
  do {                                                                         \
    const int tt_ = ((TT) < NT) ? (TT) : 0;                                    \
    const size_t gj_ = (size_t)(jbase + tt_ * 64);                             \
    _Pragma("unroll") for (int kq = 0; kq < 4; kq++) {                         \
      const int L = kq * 512 + tid;                                            \
      const int row = L >> 3, sub = L & 7;                                     \
      const int boff = (sub * 16) ^ ((row & 7) << 4);                          \
      const char* src_ = (const char*)(whT + (size_t)row * 8192 + gj_) + boff; \
      char* dst_ = (char*)ring[SLOT] + L * 16;                                 \
      __builtin_amdgcn_global_load_lds(                                        \
          (const __attribute__((address_space(1))) unsigned int*)src_,         \
          (__attribute__((address_space(3))) unsigned int*)dst_, 16, 0, 0);    \
    }                                                                          \
  } while (0)

#define FENCE asm volatile("s_waitcnt vmcnt(8)" ::: "memory")

#define MFMAPH(SLOT)                                                           \
  do {                                                                         \
    const char* lb_ = (const char*)ring[SLOT];                                 \
    _Pragma("unroll") for (int nb = 0; nb < 8; nb++) {                         \
      const int n_ = wn * 128 + nb * 16 + l16;                                 \
      const int rb_ = n_ * 128;                                                \
      const int sw_ = (n_ & 7) << 4;                                           \
      short8 fb0 = *(const short8*)(lb_ + rb_ + ((q * 16) ^ sw_));             \
      short8 fb1 = *(const short8*)(lb_ + rb_ + ((64 + q * 16) ^ sw_));        \
      accL[nb] = __builtin_amdgcn_mfma_f32_16x16x32_bf16(paL0, fb0, accL[nb], 0, 0, 0); \
      accL[nb] = __builtin_amdgcn_mfma_f32_16x16x32_bf16(paL1, fb1, accL[nb], 0, 0, 0); \
      accH[nb] = __builtin_amdgcn_mfma_f32_16x16x32_bf16(paH0, fb0, accH[nb], 0, 0, 0); \
      accH[nb] = __builtin_amdgcn_mfma_f32_16x16x32_bf16(paH1, fb1, accH[nb], 0, 0, 0); \
    }                                                                          \
  } while (0)

  // prologue
  PFLOAD(PA, 0);
  STAGE(0, 0);
  __syncthreads();  // wh2s visible

  for (int t = 0; t < NT; t += 2) {
    // even round: reads ring[0]
    PFLOAD(PB, t + 1);
    COMPUTE(PA, t);
    FENCE;
    __builtin_amdgcn_s_barrier();
    STAGE(t + 1, 1);
    MFMAPH(0);
    // odd round: reads ring[1]
    PFLOAD(PA, t + 2);
    COMPUTE(PB, t + 1);
    FENCE;
    __builtin_amdgcn_s_barrier();
    STAGE(t + 2, 0);
    MFMAPH(1);
  }

#undef PFLOAD
#undef COMPUTE
#undef STAGE
#undef FENCE
#undef MFMAPH

  float* outp = (sb == 0) ? out0 : (sb == 1) ? out1 : (sb == 2) ? out2 : out3;
  const int r0 = i0 + wm * 32 + q * 4;
#pragma unroll
  for (int nb = 0; nb < 8; nb++) {
    const int col = wn * 128 + nb * 16 + l16;
#pragma unroll
    for (int r = 0; r < 4; r++) {
      outp[(size_t)(r0 + r) * 256 + col] = accL[nb][r];
      outp[(size_t)(r0 + 16 + r) * 256 + col] = accH[nb][r];
    }
  }

  // denom: P duplicated across wn halves -> only wn==0 writes
  dsL += __shfl_xor(dsL, 16);
  dsL += __shfl_xor(dsL, 32);
  dsH += __shfl_xor(dsH, 16);
  dsH += __shfl_xor(dsH, 32);
  if (wn == 0 && lane < 16) {
    denp[sb * 8192 + i0 + wm * 32 + lane] = dsL;
    denp[sb * 8192 + i0 + wm * 32 + 16 + lane] = dsH;
  }
}

// ---------------- combine split-K partials, divide by denom, elu ----------------
__global__ __launch_bounds__(256) void k_out(float* __restrict__ out,
                                             const float* __restrict__ p1,
                                             const float* __restrict__ p2,
                                             const float* __restrict__ p3,
                                             const float* __restrict__ denp) {
  const int idx = blockIdx.x * 256 + threadIdx.x;  // grid 2048
  const int row = idx >> 6;
  float4 o = ((const float4*)out)[idx];
  float4 a = ((const float4*)p1)[idx];
  float4 b = ((const float4*)p2)[idx];
  float4 c = ((const float4*)p3)[idx];
  const float inv =
      1.0f / (denp[row] + denp[8192 + row] + denp[16384 + row] + denp[24576 + row]);
  float v0 = (o.x + a.x + b.x + c.x) * inv;
  float v1 = (o.y + a.y + b.y + c.y) * inv;
  float v2 = (o.z + a.z + b.z + c.z) * inv;
  float v3 = (o.w + a.w + b.w + c.w) * inv;
  v0 = v0 > 0.f ? v0 : expm1f(v0);
  v1 = v1 > 0.f ? v1 : expm1f(v1);
  v2 = v2 > 0.f ? v2 : expm1f(v2);
  v3 = v3 > 0.f ? v3 : expm1f(v3);
  ((float4*)out)[idx] = make_float4(v0, v1, v2, v3);
}

extern "C" void kernel_launch(void* const* d_in, const int* in_sizes, int n_in,
                              void* d_out, int out_size, void* d_ws, size_t ws_size,
                              hipStream_t stream) {
  const float* h = (const float*)d_in[0];
  const float* W = (const float*)d_in[1];
  const float* a1 = (const float*)d_in[2];
  const float* a2 = (const float*)d_in[3];
  const int* adj = (const int*)d_in[4];
  float* out = (float*)d_out;
  char* ws = (char*)d_ws;

  // ws: [whT 4MB][p1 8MB][p2 8MB][p3 8MB][denp 128K][wh1][wh2][pmax][u1][u2][gmax]
  unsigned short* whT = (unsigned short*)ws;
  float* part1 = (float*)(ws + (4u << 20));
  float* part2 = (float*)(ws + (12u << 20));
  float* part3 = (float*)(ws + (20u << 20));
  float* denp = (float*)(ws + (28u << 20));  // 4*8192
  float* wh1 = denp + 4 * 8192;
  float* wh2 = wh1 + 8192;
  float* pmax = wh2 + 8192;  // 2048
  float* u1 = pmax + 2048;
  float* u2 = u1 + 512;
  float* gmax = u2 + 512;

  hipLaunchKernelGGL(k_u, dim3(16), dim3(512), 0, stream, W, a1, a2, u1, u2);
  hipLaunchKernelGGL(k_rowvec, dim3(2048), dim3(256), 0, stream, h, u1, u2, wh1,
                     wh2, pmax);
  hipLaunchKernelGGL(k_wh, dim3(128), dim3(512), 0, stream, h, W, whT, pmax, gmax);
  hipLaunchKernelGGL(k_attn, dim3(256), dim3(512), 0, stream, adj, whT, wh1,
                     wh2, gmax, out, part1, part2, part3, denp);
  hipLaunchKernelGGL(k_out, dim3(2048), dim3(256), 0, stream, out, part1, part2,
                     part3, denp);
  (void)in_sizes; (void)n_in; (void)out_size; (void)ws_size;
}

// Round 8
// 153.438 us; speedup vs baseline: 1.0299x; 1.0000x over previous
//
#include <hip/hip_runtime.h>

// GAT layer, N=8192, F_in=512, F_out=256.
// Pipeline: k_u -> k_rowvec (wh1,wh2 pre-scaled by log2e, blockmax)
//   -> k_wh (whT bf16 GEMM; block 0 also reduces pmax->gmax)
//   -> k_attn (streams adj; P-in-registers; 8 waves = 4 row-groups x 2 col-halves,
//      fb reads shared by lo/hi row-frags; 2-slot global_load_lds ring + vmcnt(8) fence;
//      launch_bounds(512,1): VGPR cap 256 -> no spill; grid 256 -> 1 block on each CU)
//   -> k_out (combine 4 partials + elu)

typedef __attribute__((ext_vector_type(8))) short short8;
typedef __attribute__((ext_vector_type(4))) float f32x4;

#define LOG2E 1.4426950408889634f

__device__ __forceinline__ unsigned short f2bf(float f) {
  unsigned int u = __float_as_uint(f);
  unsigned int r = u + 0x7FFFu + ((u >> 16) & 1u);  // RNE
  return (unsigned short)(r >> 16);
}

// ---------------- u1 = W^T a1, u2 = W^T a2 (512 each), atomic-free ----------------
__global__ __launch_bounds__(512) void k_u(const float* __restrict__ W,
                                           const float* __restrict__ a1,
                                           const float* __restrict__ a2,
                                           float* __restrict__ u1,
                                           float* __restrict__ u2) {
  __shared__ float p1[16][32], p2[16][32];
  const int tid = threadIdx.x;
  const int kk = tid & 31, og = tid >> 5;
  const int k0 = blockIdx.x * 32;  // grid 16
  float s1 = 0.f, s2 = 0.f;
#pragma unroll
  for (int j = 0; j < 16; j++) {
    const int o = og * 16 + j;
    const float w = W[(size_t)o * 512 + k0 + kk];
    s1 += w * a1[o];
    s2 += w * a2[o];
  }
  p1[og][kk] = s1;
  p2[og][kk] = s2;
  __syncthreads();
  if (tid < 32) {
    float t1 = 0.f, t2 = 0.f;
#pragma unroll
    for (int g = 0; g < 16; g++) { t1 += p1[g][tid]; t2 += p2[g][tid]; }
    u1[k0 + tid] = t1;
    u2[k0 + tid] = t2;
  }
}

// --- wh1[i]=h_i.u1 * log2e, wh2[i]=h_i.u2 * log2e, per-block max(wh2) ---
__global__ __launch_bounds__(256) void k_rowvec(const float* __restrict__ h,
                                                const float* __restrict__ u1,
                                                const float* __restrict__ u2,
                                                float* __restrict__ wh1,
                                                float* __restrict__ wh2,
                                                float* __restrict__ pmax) {
  __shared__ float su1[512], su2[512];
  __shared__ float smax[4];
  const int tid = threadIdx.x;
  for (int i = tid; i < 512; i += 256) { su1[i] = u1[i]; su2[i] = u2[i]; }
  __syncthreads();
  const int lane = tid & 63;
  const int row = blockIdx.x * 4 + (tid >> 6);  // grid 2048
  const float* hp = h + (size_t)row * 512 + lane * 8;
  float4 x0 = *(const float4*)hp;
  float4 x1 = *(const float4*)(hp + 4);
  const float* q1 = su1 + lane * 8;
  const float* q2 = su2 + lane * 8;
  float s1 = x0.x * q1[0] + x0.y * q1[1] + x0.z * q1[2] + x0.w * q1[3]
           + x1.x * q1[4] + x1.y * q1[5] + x1.z * q1[6] + x1.w * q1[7];
  float s2 = x0.x * q2[0] + x0.y * q2[1] + x0.z * q2[2] + x0.w * q2[3]
           + x1.x * q2[4] + x1.y * q2[5] + x1.z * q2[6] + x1.w * q2[7];
#pragma unroll
  for (int off = 32; off >= 1; off >>= 1) {
    s1 += __shfl_xor(s1, off);
    s2 += __shfl_xor(s2, off);
  }
  if (lane == 0) {
    wh1[row] = s1 * LOG2E;
    wh2[row] = s2 * LOG2E;
    smax[tid >> 6] = s2 * LOG2E;
  }
  __syncthreads();
  if (tid == 0)
    pmax[blockIdx.x] = fmaxf(fmaxf(smax[0], smax[1]), fmaxf(smax[2], smax[3]));
}

// ------- whT[n][m] = (h @ W^T)[m][n] in bf16; block 0 also reduces pmax -> gmax -------
__global__ __launch_bounds__(512, 1) void k_wh(const float* __restrict__ h,
                                               const float* __restrict__ W,
                                               unsigned short* __restrict__ whT,
                                               const float* __restrict__ pmax,
                                               float* __restrict__ gmax) {
  __shared__ uint4 lds[2560];
  __shared__ float sred[8];
  const int tid = threadIdx.x;
  if (blockIdx.x == 0) {  // fold k_max: reduce pmax[2048] -> gmax
    float m = -3.0e38f;
    for (int i = tid; i < 2048; i += 512) m = fmaxf(m, pmax[i]);
#pragma unroll
    for (int off = 32; off >= 1; off >>= 1) m = fmaxf(m, __shfl_xor(m, off));
    if ((tid & 63) == 0) sred[tid >> 6] = m;
    __syncthreads();
    if (tid == 0) {
      float g = sred[0];
#pragma unroll
      for (int i = 1; i < 8; i++) g = fmaxf(g, sred[i]);
      gmax[0] = g;
    }
  }
  const int i0 = blockIdx.x * 64;  // grid 128
  const int lane = tid & 63, wid = tid >> 6;
  const int wm = wid >> 2, wn = wid & 3;
  const int l16 = lane & 15, lq = lane >> 4;
  const int hr = tid >> 3, hc = tid & 7;
  const int wr = tid >> 1, wc = tid & 1;

  f32x4 acc[2][4] = {};

  for (int t = 0; t < 8; t++) {
    const int k0 = t * 64;
    const float* hp = h + (size_t)(i0 + hr) * 512 + k0 + hc * 8;
    float4 hx = *(const float4*)hp;
    float4 hy = *(const float4*)(hp + 4);
    const float* wp = W + (size_t)wr * 512 + k0 + wc * 32;
    float4 wv[8];
#pragma unroll
    for (int q = 0; q < 8; q++) wv[q] = *(const float4*)(wp + q * 4);

    __syncthreads();
    uint4 hw;
    hw.x = (unsigned)f2bf(hx.x) | ((unsigned)f2bf(hx.y) << 16);
    hw.y = (unsigned)f2bf(hx.z) | ((unsigned)f2bf(hx.w) << 16);
    hw.z = (unsigned)f2bf(hy.x) | ((unsigned)f2bf(hy.y) << 16);
    hw.w = (unsigned)f2bf(hy.z) | ((unsigned)f2bf(hy.w) << 16);
    lds[hr * 8 + (hc ^ (hr & 7))] = hw;
#pragma unroll
    for (int q = 0; q < 4; q++) {
      uint4 ww;
      ww.x = (unsigned)f2bf(wv[2 * q].x) | ((unsigned)f2bf(wv[2 * q].y) << 16);
      ww.y = (unsigned)f2bf(wv[2 * q].z) | ((unsigned)f2bf(wv[2 * q].w) << 16);
      ww.z = (unsigned)f2bf(wv[2 * q + 1].x) | ((unsigned)f2bf(wv[2 * q + 1].y) << 16);
      ww.w = (unsigned)f2bf(wv[2 * q + 1].z) | ((unsigned)f2bf(wv[2 * q + 1].w) << 16);
      lds[512 + wr * 8 + ((wc * 4 + q) ^ (wr & 7))] = ww;
    }
    __syncthreads();
#pragma unroll
    for (int ks = 0; ks < 2; ks++) {
      const int r0 = wm * 32 + l16, r1 = r0 + 16;
      short8 fa0 = *(const short8*)&lds[r0 * 8 + ((ks * 4 + lq) ^ (r0 & 7))];
      short8 fa1 = *(const short8*)&lds[r1 * 8 + ((ks * 4 + lq) ^ (r1 & 7))];
#pragma unroll
      for (int fn = 0; fn < 4; fn++) {
        const int bn = wn * 64 + fn * 16 + l16;
        short8 fb = *(const short8*)&lds[512 + bn * 8 + ((ks * 4 + lq) ^ (bn & 7))];
        acc[0][fn] = __builtin_amdgcn_mfma_f32_16x16x32_bf16(fa0, fb, acc[0][fn], 0, 0, 0);
        acc[1][fn] = __builtin_amdgcn_mfma_f32_16x16x32_bf16(fa1, fb, acc[1][fn], 0, 0, 0);
      }
    }
  }
#pragma unroll
  for (int fm = 0; fm < 2; fm++) {
#pragma unroll
    for (int fn = 0; fn < 4; fn++) {
      const int n = wn * 64 + fn * 16 + l16;
      const int m0 = i0 + wm * 32 + fm * 16 + lq * 4;
      uint2 o;
      o.x = (unsigned)f2bf(acc[fm][fn][0]) | ((unsigned)f2bf(acc[fm][fn][1]) << 16);
      o.y = (unsigned)f2bf(acc[fm][fn][2]) | ((unsigned)f2bf(acc[fm][fn][3]) << 16);
      *(uint2*)(whT + (size_t)n * 8192 + m0) = o;
    }
  }
}

// ---------------- fused masked softmax-numerator x wh ----------------
// grid 256 = 64 row-blocks (BM=128) x 4 K-splits (2048 j); 512 thr = 8 waves
// = 4 row-groups (32 rows) x 2 col-halves (128 cols). NT=32 rounds of BK=64 j.
// launch_bounds(512,1): VGPR cap 256 (one 8-wave block/CU) -> no scratch spill.
struct PFR {
  int4 l0, l1, l2, l3, h0, h1, h2, h3;  // adj for lo/hi rows, 16 j each
};

__global__ __launch_bounds__(512, 1) void k_attn(
    const int* __restrict__ adj, const unsigned short* __restrict__ whT,
    const float* __restrict__ wh1v, const float* __restrict__ wh2v,
    const float* __restrict__ gmax,
    float* __restrict__ out0, float* __restrict__ out1,
    float* __restrict__ out2, float* __restrict__ out3,
    float* __restrict__ denp) {
  __shared__ uint4 ring[2][2048];  // 2 x 32KB whT tile [256 n][64 j] bf16
  __shared__ float wh2s[2048];     // this split's wh2 slice (log2e-scaled)
  const int NT = 32;
  const int tid = threadIdx.x;
  const int bid = blockIdx.x;
  // XCD-clustered: same sb on same XCD pair -> whT slice L2-resident
  const int sb = (bid & 7) >> 1;
  const int mb = ((bid >> 3) << 1) | (bid & 1);  // 0..63
  const int i0 = mb * 128;
  const int jbase = sb * 2048;
  const int lane = tid & 63, wid = tid >> 6;
  const int wm = wid >> 1, wn = wid & 1;  // 4 row-groups x 2 col-halves
  const int l16 = lane & 15, q = lane >> 4;
  const int row_lo = i0 + wm * 32 + l16;

  if (tid < 512) ((float4*)wh2s)[tid] = ((const float4*)(wh2v + jbase))[tid];

  const float M2 = gmax[0];
  const float w1lo = wh1v[row_lo];
  const float w1hi = wh1v[row_lo + 16];
  float tv = w1lo + M2;
  const float Milo = tv > 0.f ? tv : 0.2f * tv;
  tv = w1hi + M2;
  const float Mihi = tv > 0.f ? tv : 0.2f * tv;
  const float c1lo = w1lo - Milo, c2lo = 0.2f * w1lo - Milo;
  const float c1hi = w1hi - Mihi, c2hi = 0.2f * w1hi - Mihi;

  const int* ap_lo = adj + (size_t)row_lo * 8192 + jbase + q * 8;
  const int* ap_hi = ap_lo + 16 * 8192;

  f32x4 accL[8] = {}, accH[8] = {};
  float dsL = 0.f, dsH = 0.f;
  short8 paL0, paL1, paH0, paH1;
  PFR PA, PB;

#define PFLOAD(R, T)                              \
  do {                                            \
    const int o_ = (((T) < NT) ? (T) : 0) * 64;   \
    R.l0 = *(const int4*)(ap_lo + o_);            \
    R.l1 = *(const int4*)(ap_lo + o_ + 4);        \
    R.l2 = *(const int4*)(ap_lo + o_ + 32);       \
    R.l3 = *(const int4*)(ap_lo + o_ + 36);       \
    R.h0 = *(const int4*)(ap_hi + o_);            \
    R.h1 = *(const int4*)(ap_hi + o_ + 4);        \
    R.h2 = *(const int4*)(ap_hi + o_ + 32);       \
    R.h3 = *(const int4*)(ap_hi + o_ + 36);       \
  } while (0)

#define COMPUTE(R, T)                                                          \
  do {                                                                         \
    const int o_ = (((T) < NT) ? (T) : 0) * 64 + q * 8;                        \
    float4 z0 = *(const float4*)(wh2s + o_);                                   \
    float4 z1 = *(const float4*)(wh2s + o_ + 4);                               \
    float4 z2 = *(const float4*)(wh2s + o_ + 32);                              \
    float4 z3 = *(const float4*)(wh2s + o_ + 36);                              \
    float zv[16] = {z0.x, z0.y, z0.z, z0.w, z1.x, z1.y, z1.z, z1.w,            \
                    z2.x, z2.y, z2.z, z2.w, z3.x, z3.y, z3.z, z3.w};           \
    int al[16] = {R.l0.x, R.l0.y, R.l0.z, R.l0.w, R.l1.x, R.l1.y, R.l1.z,      \
                  R.l1.w, R.l2.x, R.l2.y, R.l2.z, R.l2.w, R.l3.x, R.l3.y,      \
                  R.l3.z, R.l3.w};                                             \
    int ah[16] = {R.h0.x, R.h0.y, R.h0.z, R.h0.w, R.h1.x, R.h1.y, R.h1.z,      \
                  R.h1.w, R.h2.x, R.h2.y, R.h2.z, R.h2.w, R.h3.x, R.h3.y,      \
                  R.h3.z, R.h3.w};                                             \
    float pl[16], ph[16];                                                      \
    _Pragma("unroll") for (int i = 0; i < 16; i++) {                           \
      float e1 = fmaxf(c1lo + zv[i], __builtin_fmaf(0.2f, zv[i], c2lo));       \
      float p = (al[i] > 0) ? __builtin_amdgcn_exp2f(e1) : 0.f;                \
      pl[i] = p;                                                               \
      dsL += p;                                                                \
      float e2 = fmaxf(c1hi + zv[i], __builtin_fmaf(0.2f, zv[i], c2hi));       \
      p = (ah[i] > 0) ? __builtin_amdgcn_exp2f(e2) : 0.f;                      \
      ph[i] = p;                                                               \
      dsH += p;                                                                \
    }                                                                          \
    _Pragma("unroll") for (int i = 0; i < 8; i++) {                            \
      paL0[i] = (short)f2bf(pl[i]);                                            \
      paL1[i] = (short)f2bf(pl[8 + i]);                                        \
      paH0[i] = (short)f2bf(ph[i]);                                            \
      paH1[i] = (short)f2bf(ph[8 + i]);                                        \
    }                                                                          \
  } while (0)

#define STAGE(TT, SLOT)                                                        \
  do {                                                                         \
    const int tt_ = ((TT) < NT) ? (TT) : 0;                                    \
    const size_t gj_ = (size_t)(jbase + tt_ * 64);                             \
    _Pragma("unroll") for (int kq = 0; kq < 4; kq++) {                         \
      const int L = kq * 512 + tid;                                            \
      const int row = L >> 3, sub = L & 7;                                     \
      const int boff = (sub * 16) ^ ((row & 7) << 4);                          \
      const char* src_ = (const char*)(whT + (size_t)row * 8192 + gj_) + boff; \
      char* dst_ = (char*)ring[SLOT] + L * 16;                                 \
      __builtin_amdgcn_global_load_lds(                                        \
          (const __attribute__((address_space(1))) unsigned int*)src_,         \
          (__attribute__((address_space(3))) unsigned int*)dst_, 16, 0, 0);    \
    }                                                                          \
  } while (0)

#define FENCE asm volatile("s_waitcnt vmcnt(8)" ::: "memory")

#define MFMAPH(SLOT)                                                           \
  do {                                                                         \
    const char* lb_ = (const char*)ring[SLOT];                                 \
    _Pragma("unroll") for (int nb = 0; nb < 8; nb++) {                         \
      const int n_ = wn * 128 + nb * 16 + l16;                                 \
      const int rb_ = n_ * 128;                                                \
      const int sw_ = (n_ & 7) << 4;                                           \
      short8 fb0 = *(const short8*)(lb_ + rb_ + ((q * 16) ^ sw_));             \
      short8 fb1 = *(const short8*)(lb_ + rb_ + ((64 + q * 16) ^ sw_));        \
      accL[nb] = __builtin_amdgcn_mfma_f32_16x16x32_bf16(paL0, fb0, accL[nb], 0, 0, 0); \
      accL[nb] = __builtin_amdgcn_mfma_f32_16x16x32_bf16(paL1, fb1, accL[nb], 0, 0, 0); \
      accH[nb] = __builtin_amdgcn_mfma_f32_16x16x32_bf16(paH0, fb0, accH[nb], 0, 0, 0); \
      accH[nb] = __builtin_amdgcn_mfma_f32_16x16x32_bf16(paH1, fb1, accH[nb], 0, 0, 0); \
    }                                                                          \
  } while (0)

  // prologue
  PFLOAD(PA, 0);
  STAGE(0, 0);
  __syncthreads();  // wh2s visible

  for (int t = 0; t < NT; t += 2) {
    // even round: reads ring[0]
    PFLOAD(PB, t + 1);
    COMPUTE(PA, t);
    FENCE;
    __builtin_amdgcn_s_barrier();
    STAGE(t + 1, 1);
    MFMAPH(0);
    // odd round: reads ring[1]
    PFLOAD(PA, t + 2);
    COMPUTE(PB, t + 1);
    FENCE;
    __builtin_amdgcn_s_barrier();
    STAGE(t + 2, 0);
    MFMAPH(1);
  }

#undef PFLOAD
#undef COMPUTE
#undef STAGE
#undef FENCE
#undef MFMAPH

  float* outp = (sb == 0) ? out0 : (sb == 1) ? out1 : (sb == 2) ? out2 : out3;
  const int r0 = i0 + wm * 32 + q * 4;
#pragma unroll
  for (int nb = 0; nb < 8; nb++) {
    const int col = wn * 128 + nb * 16 + l16;
#pragma unroll
    for (int r = 0; r < 4; r++) {
      outp[(size_t)(r0 + r) * 256 + col] = accL[nb][r];
      outp[(size_t)(r0 + 16 + r) * 256 + col] = accH[nb][r];
    }
  }

  // denom: P duplicated across wn halves -> only wn==0 writes
  dsL += __shfl_xor(dsL, 16);
  dsL += __shfl_xor(dsL, 32);
  dsH += __shfl_xor(dsH, 16);
  dsH += __shfl_xor(dsH, 32);
  if (wn == 0 && lane < 16) {
    denp[sb * 8192 + i0 + wm * 32 + lane] = dsL;
    denp[sb * 8192 + i0 + wm * 32 + 16 + lane] = dsH;
  }
}

// ---------------- combine split-K partials, divide by denom, elu ----------------
__global__ __launch_bounds__(256) void k_out(float* __restrict__ out,
                                             const float* __restrict__ p1,
                                             const float* __restrict__ p2,
                                             const float* __restrict__ p3,
                                             const float* __restrict__ denp) {
  const int idx = blockIdx.x * 256 + threadIdx.x;  // grid 2048
  const int row = idx >> 6;
  float4 o = ((const float4*)out)[idx];
  float4 a = ((const float4*)p1)[idx];
  float4 b = ((const float4*)p2)[idx];
  float4 c = ((const float4*)p3)[idx];
  const float inv =
      1.0f / (denp[row] + denp[8192 + row] + denp[16384 + row] + denp[24576 + row]);
  float v0 = (o.x + a.x + b.x + c.x) * inv;
  float v1 = (o.y + a.y + b.y + c.y) * inv;
  float v2 = (o.z + a.z + b.z + c.z) * inv;
  float v3 = (o.w + a.w + b.w + c.w) * inv;
  v0 = v0 > 0.f ? v0 : expm1f(v0);
  v1 = v1 > 0.f ? v1 : expm1f(v1);
  v2 = v2 > 0.f ? v2 : expm1f(v2);
  v3 = v3 > 0.f ? v3 : expm1f(v3);
  ((float4*)out)[idx] = make_float4(v0, v1, v2, v3);
}

extern "C" void kernel_launch(void* const* d_in, const int* in_sizes, int n_in,
                              void* d_out, int out_size, void* d_ws, size_t ws_size,
                              hipStream_t stream) {
  const float* h = (const float*)d_in[0];
  const float* W = (const float*)d_in[1];
  const float* a1 = (const float*)d_in[2];
  const float* a2 = (const float*)d_in[3];
  const int* adj = (const int*)d_in[4];
  float* out = (float*)d_out;
  char* ws = (char*)d_ws;

  // ws: [whT 4MB][p1 8MB][p2 8MB][p3 8MB][denp 128K][wh1][wh2][pmax][u1][u2][gmax]
  unsigned short* whT = (unsigned short*)ws;
  float* part1 = (float*)(ws + (4u << 20));
  float* part2 = (float*)(ws + (12u << 20));
  float* part3 = (float*)(ws + (20u << 20));
  float* denp = (float*)(ws + (28u << 20));  // 4*8192
  float* wh1 = denp + 4 * 8192;
  float* wh2 = wh1 + 8192;
  float* pmax = wh2 + 8192;  // 2048
  float* u1 = pmax + 2048;
  float* u2 = u1 + 512;
  float* gmax = u2 + 512;

  hipLaunchKernelGGL(k_u, dim3(16), dim3(512), 0, stream, W, a1, a2, u1, u2);
  hipLaunchKernelGGL(k_rowvec, dim3(2048), dim3(256), 0, stream, h, u1, u2, wh1,
                     wh2, pmax);
  hipLaunchKernelGGL(k_wh, dim3(128), dim3(512), 0, stream, h, W, whT, pmax, gmax);
  hipLaunchKernelGGL(k_attn, dim3(256), dim3(512), 0, stream, adj, whT, wh1,
                     wh2, gmax, out, part1, part2, part3, denp);
  hipLaunchKernelGGL(k_out, dim3(2048), dim3(256), 0, stream, out, part1, part2,
                     part3, denp);
  (void)in_sizes; (void)n_in; (void)out_size; (void)ws_size;
}